// Round 5
// baseline (4570.921 us; speedup 1.0000x reference)
//
#include <hip/hip_runtime.h>
#include <math.h>

typedef __attribute__((ext_vector_type(8))) short s16x8;
typedef __attribute__((ext_vector_type(4))) float f32x4;
typedef unsigned long long ull;

constexpr float LOG2E = 1.4426950408889634f;

__device__ __forceinline__ unsigned short f2bf(float f) {
  unsigned int x = __builtin_bit_cast(unsigned int, f);
  x += 0x7fffu + ((x >> 16) & 1u);          // RNE
  return (unsigned short)(x >> 16);
}
__device__ __forceinline__ float fexp2(float x) { return __builtin_amdgcn_exp2f(x); }
__device__ __forceinline__ float frcp(float x)  { return __builtin_amdgcn_rcpf(x); }

#define MFMA16(A, B, Cc) __builtin_amdgcn_mfma_f32_16x16x32_bf16((A), (B), (Cc), 0, 0, 0)

constexpr int TT = 512;
constexpr int NB = 1024;
constexpr int CH = 2;     // steps per chunk

// ---------------------------------------------------------------------------
// Per-layer scan, 32 batch rows/block, 16 waves (2 row-groups x 8 waves).
// Waves 0-7: rows [0,16); waves 8-15: rows [16,32) -- independent MFMA tiles,
// same weights (per-wave register copies). Doubles issue work per CU so the
// dependency-chain bubbles (ds_read->MFMA->trans->ds_write) get filled.
// Per chunk of CH=2 steps: publish lagged flag | burst x-GEMM | prefetch |
// chain step 0 | barrier | chain step 1 + stage next x | barrier.
// Flag F => ys steps < F*CH visible at MALL (drained by end-of-chunk
// __syncthreads vmcnt(0), published at the TOP of the next chunk).
// ---------------------------------------------------------------------------
template <int DIN, bool FIRST, bool LAST>
__device__ __forceinline__ void scan_layer(
    unsigned short* x_s,                      // [CH][32][DIN] swizzled
    unsigned short* h_s,                      // [2][32][128] swizzled
    float* b_s,                               // [512] pre-scaled bias
    const float* __restrict__ xin,            // FIRST: x [B][T][32] f32
    unsigned short* ys,                       // [T][B][128] bf16 pipe (in-place)
    const float* __restrict__ Wih, const float* __restrict__ Whh,
    const float* __restrict__ bias, float* __restrict__ hT,
    int* prog_in, int* prog_out, int bblk)
{
  constexpr int KTX = DIN / 32;               // 1 or 4 x k-tiles
  constexpr int XM  = (DIN == 32) ? 3 : 7;    // x-tile swizzle row mask
  const int tid = threadIdx.x;
  const int wv = tid >> 6, ln = tid & 63, l15 = ln & 15, lg = ln >> 4;
  const int rg = wv >> 3, wv8 = wv & 7;       // row-group, col-tile wave
  const int arow = rg * 16 + l15;             // my batch row within block
  const int row0 = bblk * 32;
  const int prow = tid >> 5, pcol = tid & 31; // staging: 32 rows x 32 cols

  // ---- weights -> regs (bf16, pre-scaled by -log2e / 2log2e) ----
  s16x8 bfx[4][KTX], bfh[4][4];
#pragma unroll
  for (int j = 0; j < 4; ++j) {
    const float sc = (j == 2) ? (2.0f * LOG2E) : (-LOG2E);
    const int n = j * 128 + wv8 * 16 + l15;
#pragma unroll
    for (int kt = 0; kt < KTX; ++kt) {
      s16x8 f;
#pragma unroll
      for (int e = 0; e < 8; ++e) f[e] = (short)f2bf(Wih[n * DIN + kt * 32 + lg * 8 + e] * sc);
      bfx[j][kt] = f;
    }
#pragma unroll
    for (int kt = 0; kt < 4; ++kt) {
      s16x8 f;
#pragma unroll
      for (int e = 0; e < 8; ++e) f[e] = (short)f2bf(Whh[n * 128 + kt * 32 + lg * 8 + e] * sc);
      bfh[j][kt] = f;
    }
  }
  if (tid < 512) b_s[tid] = bias[tid] * ((tid >> 7) == 2 ? 2.0f * LOG2E : -LOG2E);
  for (int i = tid; i < 2 * 32 * 128; i += 1024) h_s[i] = 0;  // h0 = 0

  // ---- prologue: acquire + stage chunk 0 ----
  float xrf[CH];
  ull xrh[CH];
  int avail = 0;
  if (FIRST) {
#pragma unroll
    for (int s = 0; s < CH; ++s) {
      xrf[s] = xin[(size_t)(row0 + prow) * (TT * 32) + s * 32 + pcol];
      x_s[s * (32 * DIN) + prow * DIN + (pcol ^ ((prow & XM) << 3))] = f2bf(xrf[s]);
    }
  } else {
    int f;
    do { f = __hip_atomic_load(prog_in, __ATOMIC_RELAXED, __HIP_MEMORY_SCOPE_AGENT); } while (f < 1);
    avail = f * CH;
    const int e = tid * 4, r = e >> 7, k = e & 127;
#pragma unroll
    for (int s = 0; s < CH; ++s) {
      xrh[s] = __hip_atomic_load(
          (ull*)ys + ((size_t)s * (NB * 128) + (size_t)(row0 + r) * 128 + k) / 4,
          __ATOMIC_RELAXED, __HIP_MEMORY_SCOPE_AGENT);
      *reinterpret_cast<ull*>(
          &x_s[s * (32 * DIN) + r * DIN + (k ^ ((r & 7) << 3))]) = xrh[s];
    }
  }
  __syncthreads();                            // x_s + h0 + b_s visible, vm drained

  float cst[4] = {0.f, 0.f, 0.f, 0.f};
  const int hcol = wv8 * 16 + lg * 4;         // my 4 cells (batch row arow)

  for (int t0 = 0; t0 < TT; t0 += CH) {
    const int t1 = t0 + CH;

    // ---- lagged flag publish: steps < t0 drained by last chunk's barrier ----
    if (!LAST && tid == 0 && t0 > 0)
      __hip_atomic_store(prog_out, t0 / CH, __ATOMIC_RELAXED, __HIP_MEMORY_SCOPE_AGENT);

    // ---- burst: gx[s][j] = bias + x@Wih^T (off the chain) ----
    f32x4 gx[CH][4];
#pragma unroll
    for (int s = 0; s < CH; ++s) {
#pragma unroll
      for (int j = 0; j < 4; ++j)
        gx[s][j] = *reinterpret_cast<const f32x4*>(&b_s[j * 128 + wv8 * 16 + lg * 4]);
#pragma unroll
      for (int kt = 0; kt < KTX; ++kt) {
        const s16x8 xf = *reinterpret_cast<const s16x8*>(
            &x_s[s * (32 * DIN) + arow * DIN + ((kt * 32 + lg * 8) ^ ((arow & XM) << 3))]);
#pragma unroll
        for (int j = 0; j < 4; ++j) gx[s][j] = MFMA16(bfx[j][kt], xf, gx[s][j]);
      }
    }

    // ---- prefetch next chunk's input into regs ----
    if (t1 < TT) {
      if (FIRST) {
#pragma unroll
        for (int s = 0; s < CH; ++s)
          xrf[s] = xin[(size_t)(row0 + prow) * (TT * 32) + (t1 + s) * 32 + pcol];
      } else {
        if (avail < t1 + CH) {
          int f;
          do { f = __hip_atomic_load(prog_in, __ATOMIC_RELAXED, __HIP_MEMORY_SCOPE_AGENT); } while (f * CH < t1 + CH);
          avail = f * CH;
        }
        const int e = tid * 4, r = e >> 7, k = e & 127;
#pragma unroll
        for (int s = 0; s < CH; ++s)
          xrh[s] = __hip_atomic_load(
              (ull*)ys + ((size_t)(t1 + s) * (NB * 128) + (size_t)(row0 + r) * 128 + k) / 4,
              __ATOMIC_RELAXED, __HIP_MEMORY_SCOPE_AGENT);
      }
    }

    // ---- chain: CH recurrent steps, K=128 only ----
#pragma unroll
    for (int s = 0; s < CH; ++s) {
      const int t = t0 + s;
      if (s) __syncthreads();                 // h(t) visible
      unsigned short* buf  = h_s + (t & 1) * (32 * 128);
      unsigned short* nbuf = h_s + ((t + 1) & 1) * (32 * 128);
      s16x8 afr[4];
#pragma unroll
      for (int kt = 0; kt < 4; ++kt)
        afr[kt] = *reinterpret_cast<const s16x8*>(
            &buf[arow * 128 + ((kt * 32 + lg * 8) ^ ((arow & 7) << 3))]);
      f32x4 acc[4];
#pragma unroll
      for (int j = 0; j < 4; ++j) acc[j] = gx[s][j];
#pragma unroll
      for (int kt = 0; kt < 4; ++kt)
#pragma unroll
        for (int j = 0; j < 4; ++j) acc[j] = MFMA16(bfh[j][kt], afr[kt], acc[j]);

      float hv[4];
#pragma unroll
      for (int r = 0; r < 4; ++r) {
        const float iv = frcp(1.0f + fexp2(acc[0][r]));
        const float fv = frcp(1.0f + fexp2(acc[1][r]));
        const float gv = 1.0f - 2.0f * frcp(1.0f + fexp2(acc[2][r]));
        const float ov = frcp(1.0f + fexp2(acc[3][r]));
        const float cn = fv * cst[r] + iv * gv;
        cst[r] = cn;
        const float th = 1.0f - 2.0f * frcp(1.0f + fexp2(cn * (2.0f * LOG2E)));
        hv[r] = ov * th;
      }
      unsigned int plo, phi;
      asm("v_cvt_pk_bf16_f32 %0, %1, %2" : "=v"(plo) : "v"(hv[0]), "v"(hv[1]));
      asm("v_cvt_pk_bf16_f32 %0, %1, %2" : "=v"(phi) : "v"(hv[2]), "v"(hv[3]));
      const ull hpack = (ull)plo | ((ull)phi << 32);

      *reinterpret_cast<ull*>(&nbuf[arow * 128 + (hcol ^ ((arow & 7) << 3))]) = hpack;

      if (!LAST) {
        __hip_atomic_store(
            (ull*)ys + ((size_t)t * (NB * 128) + (size_t)(row0 + arow) * 128 + hcol) / 4,
            hpack, __ATOMIC_RELAXED, __HIP_MEMORY_SCOPE_AGENT);
      } else if (t == TT - 1) {
        f32x4 o = {hv[0], hv[1], hv[2], hv[3]};
        *reinterpret_cast<f32x4*>(&hT[(row0 + arow) * 128 + hcol]) = o;  // f32 for LN
      }

      // last chain step: stage next chunk's x tile before the closing barrier
      if (s == CH - 1 && t1 < TT) {
        if (FIRST) {
#pragma unroll
          for (int ss = 0; ss < CH; ++ss)
            x_s[ss * (32 * DIN) + prow * DIN + (pcol ^ ((prow & XM) << 3))] = f2bf(xrf[ss]);
        } else {
          const int e = tid * 4, r = e >> 7, k = e & 127;
#pragma unroll
          for (int ss = 0; ss < CH; ++ss)
            *reinterpret_cast<ull*>(
                &x_s[ss * (32 * DIN) + r * DIN + (k ^ ((r & 7) << 3))]) = xrh[ss];
        }
      }
    }
    __syncthreads();  // h(t0+CH) + next x_s visible; this chunk's ys stores drained
  }

  if (!LAST && tid == 0)
    __hip_atomic_store(prog_out, TT / CH, __ATOMIC_RELAXED, __HIP_MEMORY_SCOPE_AGENT);
}

__global__ __launch_bounds__(1024, 4) void lstm_fused(
    const float* __restrict__ x, unsigned short* ys,
    const float* __restrict__ Wih0, const float* __restrict__ Whh0, const float* __restrict__ b0,
    const float* __restrict__ Wih1, const float* __restrict__ Whh1, const float* __restrict__ b1,
    const float* __restrict__ Wih2, const float* __restrict__ Whh2, const float* __restrict__ b2,
    float* __restrict__ hT, int* prog)
{
  __shared__ unsigned short x_s[CH * 32 * 128];
  __shared__ unsigned short h_s[2 * 32 * 128];
  __shared__ float b_s[512];
  const int lay = blockIdx.x >> 5;            // 0..2
  const int bblk = blockIdx.x & 31;           // 0..31 (32 rows each)
  if (lay == 0) {
    scan_layer<32, true, false>(x_s, h_s, b_s, x, ys, Wih0, Whh0, b0, nullptr,
                                nullptr, &prog[(0 * 32 + bblk) * 16], bblk);
  } else if (lay == 1) {
    scan_layer<128, false, false>(x_s, h_s, b_s, nullptr, ys, Wih1, Whh1, b1, nullptr,
                                  &prog[(0 * 32 + bblk) * 16], &prog[(1 * 32 + bblk) * 16], bblk);
  } else {
    scan_layer<128, false, true>(x_s, h_s, b_s, nullptr, ys, Wih2, Whh2, b2, hT,
                                 &prog[(1 * 32 + bblk) * 16], nullptr, bblk);
  }
}

__global__ void init_flags(int* prog) {
  prog[threadIdx.x] = 0;
  prog[threadIdx.x + 1024] = 0;
}

// ---------------------------------------------------------------------------
// Head: LN + fc1 + fc2 + 4 heads + reparam + dec1 + dec2 + out. 4 rows/block.
// ---------------------------------------------------------------------------
__global__ __launch_bounds__(256) void head_kernel(
    const float* __restrict__ hT, const float* __restrict__ eps,
    const float* __restrict__ u, const float* __restrict__ choice,
    const float* __restrict__ ln_g, const float* __restrict__ ln_b,
    const float* __restrict__ fc1_W, const float* __restrict__ fc1_b,
    const float* __restrict__ fc2_W, const float* __restrict__ fc2_b,
    const float* __restrict__ mean_W, const float* __restrict__ mean_b,
    const float* __restrict__ logvar_W, const float* __restrict__ logvar_b,
    const float* __restrict__ scale_W, const float* __restrict__ scale_b,
    const float* __restrict__ shape_W, const float* __restrict__ shape_b,
    const float* __restrict__ dec1_W, const float* __restrict__ dec1_b,
    const float* __restrict__ dec2_W, const float* __restrict__ dec2_b,
    const float* __restrict__ out_W, const float* __restrict__ out_b,
    const float* __restrict__ pi_params, float* __restrict__ out)
{
  __shared__ float s_hn[4][128];
  __shared__ float s_a[4][128];
  __shared__ float s_b2[4][64];
  __shared__ float s_z[4][64];
  __shared__ float s_d1[4][128];
  __shared__ float s_d2[4][512];

  const int tid = threadIdx.x;
  const int gr0 = blockIdx.x * 4;

  { // LayerNorm: one wave per row
    const int wvr = tid >> 6, lnn = tid & 63;
    const float v0 = hT[(gr0 + wvr) * 128 + lnn];
    const float v1 = hT[(gr0 + wvr) * 128 + 64 + lnn];
    float s = v0 + v1, s2 = v0 * v0 + v1 * v1;
#pragma unroll
    for (int off = 32; off; off >>= 1) {
      s  += __shfl_xor(s, off, 64);
      s2 += __shfl_xor(s2, off, 64);
    }
    const float mu  = s * (1.f / 128.f);
    const float var = s2 * (1.f / 128.f) - mu * mu;
    const float rs  = rsqrtf(var + 1e-5f);
    s_hn[wvr][lnn]      = (v0 - mu) * rs * ln_g[lnn]      + ln_b[lnn];
    s_hn[wvr][lnn + 64] = (v1 - mu) * rs * ln_g[lnn + 64] + ln_b[lnn + 64];
  }
  __syncthreads();
#pragma unroll
  for (int p = 0; p < 2; ++p) { // fc1 (128x128) + relu
    const int idx = tid + p * 256, row = idx >> 7, col = idx & 127;
    const float* w = fc1_W + col * 128;
    float a = fc1_b[col];
    for (int k = 0; k < 128; k += 4)
      a += s_hn[row][k] * w[k] + s_hn[row][k + 1] * w[k + 1] +
           s_hn[row][k + 2] * w[k + 2] + s_hn[row][k + 3] * w[k + 3];
    s_a[row][col] = fmaxf(a, 0.f);
  }
  __syncthreads();
  { // fc2 (64x128) + relu
    const int row = tid >> 6, col = tid & 63;
    const float* w = fc2_W + col * 128;
    float a = fc2_b[col];
    for (int k = 0; k < 128; ++k) a += s_a[row][k] * w[k];
    s_b2[row][col] = fmaxf(a, 0.f);
  }
  __syncthreads();
  { // 4 heads + reparameterize
    const int row = tid >> 6, c = tid & 63;
    const int gr = gr0 + row;
    float am = mean_b[c], al = logvar_b[c], as_ = scale_b[c], ah = shape_b[c];
    for (int k = 0; k < 64; ++k) {
      const float hv = s_b2[row][k];
      am  += hv * mean_W[c * 64 + k];
      al  += hv * logvar_W[c * 64 + k];
      as_ += hv * scale_W[c * 64 + k];
      ah  += hv * shape_W[c * 64 + k];
    }
    const float zsc = fexp2(as_ * LOG2E);
    const float zsh = fmaxf(ah, 1e-6f);
    out[131072 + gr * 64 + c] = am;
    out[196608 + gr * 64 + c] = al;
    out[262144 + gr * 64 + c] = zsc;
    out[327680 + gr * 64 + c] = zsh;
    const float ev = eps[gr * 64 + c], uv = u[gr * 64 + c], cv = choice[gr];
    const float zg = am + ev * fexp2(0.72134752044448170f * al);  // exp(0.5*logvar)
    const float p0 = pi_params[0], p1 = pi_params[1];
    const float pi0 = 1.f / (1.f + expf(p1 - p0));
    const float tq = -zsh * logf(1.f - uv);                       // expm1: no cancel
    const float zp = zsc * frcp(zsh) * expm1f(tq);
    s_z[row][c] = (cv < pi0) ? zg : zp;
  }
  __syncthreads();
#pragma unroll
  for (int p = 0; p < 2; ++p) { // dec1 (128x64) + relu
    const int idx = tid + p * 256, row = idx >> 7, col = idx & 127;
    const float* w = dec1_W + col * 64;
    float a = dec1_b[col];
    for (int k = 0; k < 64; ++k) a += s_z[row][k] * w[k];
    s_d1[row][col] = fmaxf(a, 0.f);
  }
  __syncthreads();
  for (int o = tid; o < 2000; o += 256) { // dec2 (500x128) + relu
    const int row = o / 500, col = o % 500;
    const float* w = dec2_W + col * 128;
    float a = dec2_b[col];
    for (int k = 0; k < 128; ++k) a += s_d1[row][k] * w[k];
    s_d2[row][col] = fmaxf(a, 0.f);
  }
  __syncthreads();
#pragma unroll
  for (int p = 0; p < 2; ++p) { // out (128x500)
    const int idx = tid + p * 256, row = idx >> 7, col = idx & 127;
    const float* w = out_W + col * 500;
    float a = out_b[col];
    for (int k = 0; k < 500; ++k) a += s_d2[row][k] * w[k];
    out[(gr0 + row) * 128 + col] = a;
  }
}

// ---------------------------------------------------------------------------
extern "C" void kernel_launch(void* const* d_in, const int* in_sizes, int n_in,
                              void* d_out, int out_size, void* d_ws, size_t ws_size,
                              hipStream_t stream) {
  const float* x      = (const float*)d_in[0];
  const float* eps    = (const float*)d_in[1];
  const float* u      = (const float*)d_in[2];
  const float* choice = (const float*)d_in[3];
  const float* Wih0 = (const float*)d_in[4],  *Whh0 = (const float*)d_in[5],  *b0 = (const float*)d_in[6];
  const float* Wih1 = (const float*)d_in[7],  *Whh1 = (const float*)d_in[8],  *b1 = (const float*)d_in[9];
  const float* Wih2 = (const float*)d_in[10], *Whh2 = (const float*)d_in[11], *b2 = (const float*)d_in[12];
  const float* ln_g = (const float*)d_in[13], *ln_b = (const float*)d_in[14];
  const float* fc1_W = (const float*)d_in[15], *fc1_b = (const float*)d_in[16];
  const float* fc2_W = (const float*)d_in[17], *fc2_b = (const float*)d_in[18];
  const float* mean_W = (const float*)d_in[19], *mean_b = (const float*)d_in[20];
  const float* logvar_W = (const float*)d_in[21], *logvar_b = (const float*)d_in[22];
  const float* scale_W = (const float*)d_in[23], *scale_b = (const float*)d_in[24];
  const float* shape_W = (const float*)d_in[25], *shape_b = (const float*)d_in[26];
  const float* dec1_W = (const float*)d_in[27], *dec1_b = (const float*)d_in[28];
  const float* dec2_W = (const float*)d_in[29], *dec2_b = (const float*)d_in[30];
  const float* out_W = (const float*)d_in[31], *out_b = (const float*)d_in[32];
  const float* pi_params = (const float*)d_in[33];

  unsigned short* ys = (unsigned short*)d_ws;                        // 128 MiB
  float* hT  = (float*)((char*)d_ws + (size_t)512 * 1024 * 128 * 2); // 512 KiB
  int*   prog = (int*)((char*)d_ws + (size_t)512 * 1024 * 128 * 2 + (size_t)1024 * 128 * 4);

  init_flags<<<1, 1024, 0, stream>>>(prog);
  lstm_fused<<<96, 1024, 0, stream>>>(x, ys, Wih0, Whh0, b0, Wih1, Whh1, b1,
                                      Wih2, Whh2, b2, hT, prog);
  head_kernel<<<256, 256, 0, stream>>>(hT, eps, u, choice, ln_g, ln_b,
      fc1_W, fc1_b, fc2_W, fc2_b, mean_W, mean_b, logvar_W, logvar_b,
      scale_W, scale_b, shape_W, shape_b, dec1_W, dec1_b, dec2_W, dec2_b,
      out_W, out_b, pi_params, (float*)d_out);
}

// Round 6
// 655.225 us; speedup vs baseline: 6.9761x; 6.9761x over previous
//
#include <hip/hip_runtime.h>
#include <math.h>

typedef __attribute__((ext_vector_type(8))) short s16x8;
typedef __attribute__((ext_vector_type(4))) float f32x4;
typedef unsigned long long ull;

constexpr float LOG2E = 1.4426950408889634f;

__device__ __forceinline__ unsigned short f2bf(float f) {
  unsigned int x = __builtin_bit_cast(unsigned int, f);
  x += 0x7fffu + ((x >> 16) & 1u);          // RNE
  return (unsigned short)(x >> 16);
}
__device__ __forceinline__ float fexp2(float x) { return __builtin_amdgcn_exp2f(x); }
__device__ __forceinline__ float frcp(float x)  { return __builtin_amdgcn_rcpf(x); }

#define MFMA16(A, B, Cc) __builtin_amdgcn_mfma_f32_16x16x32_bf16((A), (B), (Cc), 0, 0, 0)

constexpr int TT = 512;
constexpr int NB = 1024;
constexpr int CH = 2;     // steps per chunk

// ---------------------------------------------------------------------------
// Per-layer scan, 16 batch rows/block, 8 waves (identical structure to the
// 658us baseline). Per chunk of CH=2 steps:
//   [flag load issued | prefetch issued (steady path)] -> burst x-GEMM ->
//   chain step 0 -> sync -> chain step 1 -> stage next x -> sync.
// The ONLY change vs baseline: the cross-layer flag is pipelined (issued at
// chunk top, absorbed at chunk end) and prefetch loads issue at chunk top,
// so no MALL round-trip sits on the per-chunk critical path in steady state.
// Flag F => ys steps < F*CH visible at MALL (publish lagged one chunk after
// the draining __syncthreads, as in the baseline).
// ---------------------------------------------------------------------------
template <int DIN, bool FIRST, bool LAST>
__device__ __forceinline__ void scan_layer(
    unsigned short* x_s,                      // [CH][16][DIN] swizzled
    unsigned short* h_s,                      // [2][16][128] swizzled
    float* b_s,                               // [512] pre-scaled bias
    const float* __restrict__ xin,            // FIRST: x [B][T][32] f32
    unsigned short* ys,                       // [T][B][128] bf16 pipe (in-place)
    const float* __restrict__ Wih, const float* __restrict__ Whh,
    const float* __restrict__ bias, float* __restrict__ hT,
    int* prog_in, int* prog_out, int bblk)
{
  constexpr int KTX = DIN / 32;               // 1 or 4 x k-tiles
  constexpr int XM  = (DIN == 32) ? 3 : 7;    // x-tile swizzle row mask
  const int tid = threadIdx.x;
  const int wv = tid >> 6, ln = tid & 63, l15 = ln & 15, lg = ln >> 4;
  const int row0 = bblk * 16;
  const int prow = tid >> 5, pcol = tid & 31;

  // ---- weights -> regs (bf16, pre-scaled by -log2e / 2log2e) ----
  s16x8 bfx[4][KTX], bfh[4][4];
#pragma unroll
  for (int j = 0; j < 4; ++j) {
    const float sc = (j == 2) ? (2.0f * LOG2E) : (-LOG2E);
    const int n = j * 128 + wv * 16 + l15;
#pragma unroll
    for (int kt = 0; kt < KTX; ++kt) {
      s16x8 f;
#pragma unroll
      for (int e = 0; e < 8; ++e) f[e] = (short)f2bf(Wih[n * DIN + kt * 32 + lg * 8 + e] * sc);
      bfx[j][kt] = f;
    }
#pragma unroll
    for (int kt = 0; kt < 4; ++kt) {
      s16x8 f;
#pragma unroll
      for (int e = 0; e < 8; ++e) f[e] = (short)f2bf(Whh[n * 128 + kt * 32 + lg * 8 + e] * sc);
      bfh[j][kt] = f;
    }
  }
  b_s[tid] = bias[tid] * ((tid >> 7) == 2 ? 2.0f * LOG2E : -LOG2E);
  for (int i = tid; i < 2 * 16 * 128; i += 512) h_s[i] = 0;   // h0 = 0

  // ---- prologue: acquire + stage chunk 0 ----
  float xrf[CH];
  ull xrh[CH];
  int avail = 0;
  if (FIRST) {
#pragma unroll
    for (int s = 0; s < CH; ++s) {
      xrf[s] = xin[(size_t)(row0 + prow) * (TT * 32) + s * 32 + pcol];
      x_s[s * (16 * DIN) + prow * DIN + (pcol ^ ((prow & XM) << 3))] = f2bf(xrf[s]);
    }
  } else {
    int f;
    do { f = __hip_atomic_load(prog_in, __ATOMIC_RELAXED, __HIP_MEMORY_SCOPE_AGENT); } while (f < 1);
    avail = f * CH;
#pragma unroll
    for (int s = 0; s < CH; ++s) {
      xrh[s] = __hip_atomic_load(
          (ull*)ys + ((size_t)s * (NB * 128) + (size_t)(row0 + prow) * 128 + pcol * 4) / 4,
          __ATOMIC_RELAXED, __HIP_MEMORY_SCOPE_AGENT);
      *reinterpret_cast<ull*>(
          &x_s[s * (16 * DIN) + prow * DIN + ((pcol * 4) ^ ((prow & 7) << 3))]) = xrh[s];
    }
  }
  __syncthreads();                            // x_s + h0 + b_s visible

  float cst[4] = {0.f, 0.f, 0.f, 0.f};
  const int hcol = wv * 16 + lg * 4;          // my 4 cells (batch row l15)

  for (int t0 = 0; t0 < TT; t0 += CH) {
    const int t1 = t0 + CH;

    // ---- lagged flag publish (stores < t0 drained by last chunk's sync) ----
    if (!LAST && tid == 0 && t0 > 0)
      __hip_atomic_store(prog_out, t0 / CH, __ATOMIC_RELAXED, __HIP_MEMORY_SCOPE_AGENT);

    // ---- async flag read: issued now, absorbed at chunk end ----
    int f_new = 0;
    if (!FIRST && t1 < TT)
      f_new = __hip_atomic_load(prog_in, __ATOMIC_RELAXED, __HIP_MEMORY_SCOPE_AGENT);

    // ---- prefetch next chunk's input at chunk TOP (steady path) ----
    bool prefetched = false;
    if (t1 < TT) {
      if (FIRST) {
#pragma unroll
        for (int s = 0; s < CH; ++s)
          xrf[s] = xin[(size_t)(row0 + prow) * (TT * 32) + (t1 + s) * 32 + pcol];
        prefetched = true;
      } else if (avail >= t1 + CH) {
#pragma unroll
        for (int s = 0; s < CH; ++s)
          xrh[s] = __hip_atomic_load(
              (ull*)ys + ((size_t)(t1 + s) * (NB * 128) + (size_t)(row0 + prow) * 128 + pcol * 4) / 4,
              __ATOMIC_RELAXED, __HIP_MEMORY_SCOPE_AGENT);
        prefetched = true;
      }
    }

    // ---- burst: gx[s][j] = bias + x@Wih^T (off the chain) ----
    f32x4 gx[CH][4];
#pragma unroll
    for (int s = 0; s < CH; ++s) {
#pragma unroll
      for (int j = 0; j < 4; ++j)
        gx[s][j] = *reinterpret_cast<const f32x4*>(&b_s[j * 128 + wv * 16 + lg * 4]);
#pragma unroll
      for (int kt = 0; kt < KTX; ++kt) {
        const s16x8 xf = *reinterpret_cast<const s16x8*>(
            &x_s[s * (16 * DIN) + l15 * DIN + ((kt * 32 + lg * 8) ^ ((l15 & XM) << 3))]);
#pragma unroll
        for (int j = 0; j < 4; ++j) gx[s][j] = MFMA16(bfx[j][kt], xf, gx[s][j]);
      }
    }

    // ---- slow path: flag shortfall -> spin (startup / producer hiccup) ----
    if (t1 < TT && !prefetched) {
      int f = f_new;
      while (f * CH < t1 + CH)
        f = __hip_atomic_load(prog_in, __ATOMIC_RELAXED, __HIP_MEMORY_SCOPE_AGENT);
      f_new = f;
      avail = f * CH;
#pragma unroll
      for (int s = 0; s < CH; ++s)
        xrh[s] = __hip_atomic_load(
            (ull*)ys + ((size_t)(t1 + s) * (NB * 128) + (size_t)(row0 + prow) * 128 + pcol * 4) / 4,
            __ATOMIC_RELAXED, __HIP_MEMORY_SCOPE_AGENT);
    }

    // ---- chain: CH recurrent steps, K=128 only ----
#pragma unroll
    for (int s = 0; s < CH; ++s) {
      const int t = t0 + s;
      if (s) __syncthreads();                 // h(t) visible
      unsigned short* buf  = h_s + (t & 1) * (16 * 128);
      unsigned short* nbuf = h_s + ((t + 1) & 1) * (16 * 128);
      s16x8 afr[4];
#pragma unroll
      for (int kt = 0; kt < 4; ++kt)
        afr[kt] = *reinterpret_cast<const s16x8*>(
            &buf[l15 * 128 + ((kt * 32 + lg * 8) ^ ((l15 & 7) << 3))]);
      f32x4 acc[4];
#pragma unroll
      for (int j = 0; j < 4; ++j) acc[j] = gx[s][j];
#pragma unroll
      for (int kt = 0; kt < 4; ++kt)
#pragma unroll
        for (int j = 0; j < 4; ++j) acc[j] = MFMA16(bfh[j][kt], afr[kt], acc[j]);

      float hv[4];
#pragma unroll
      for (int r = 0; r < 4; ++r) {
        const float iv = frcp(1.0f + fexp2(acc[0][r]));
        const float fv = frcp(1.0f + fexp2(acc[1][r]));
        const float gv = 1.0f - 2.0f * frcp(1.0f + fexp2(acc[2][r]));
        const float ov = frcp(1.0f + fexp2(acc[3][r]));
        const float cn = fv * cst[r] + iv * gv;
        cst[r] = cn;
        const float th = 1.0f - 2.0f * frcp(1.0f + fexp2(cn * (2.0f * LOG2E)));
        hv[r] = ov * th;
      }
      unsigned int plo, phi;
      asm("v_cvt_pk_bf16_f32 %0, %1, %2" : "=v"(plo) : "v"(hv[0]), "v"(hv[1]));
      asm("v_cvt_pk_bf16_f32 %0, %1, %2" : "=v"(phi) : "v"(hv[2]), "v"(hv[3]));
      const ull hpack = (ull)plo | ((ull)phi << 32);

      *reinterpret_cast<ull*>(&nbuf[l15 * 128 + (hcol ^ ((l15 & 7) << 3))]) = hpack;

      if (!LAST) {
        __hip_atomic_store(
            (ull*)ys + ((size_t)t * (NB * 128) + (size_t)(row0 + l15) * 128 + hcol) / 4,
            hpack, __ATOMIC_RELAXED, __HIP_MEMORY_SCOPE_AGENT);
      } else if (t == TT - 1) {
        f32x4 o = {hv[0], hv[1], hv[2], hv[3]};
        *reinterpret_cast<f32x4*>(&hT[(row0 + l15) * 128 + hcol]) = o;  // f32 for LN
      }

      // last chain step: stage next chunk's x tile before the closing sync
      if (s == CH - 1 && t1 < TT) {
        if (FIRST) {
#pragma unroll
          for (int ss = 0; ss < CH; ++ss)
            x_s[ss * (16 * DIN) + prow * DIN + (pcol ^ ((prow & XM) << 3))] = f2bf(xrf[ss]);
        } else {
#pragma unroll
          for (int ss = 0; ss < CH; ++ss)
            *reinterpret_cast<ull*>(
                &x_s[ss * (16 * DIN) + prow * DIN + ((pcol * 4) ^ ((prow & 7) << 3))]) = xrh[ss];
        }
      }
    }

    // ---- absorb async flag (vmcnt wait lands here, ~2 steps after issue) ----
    if (!FIRST && t1 < TT) {
      const int a2 = f_new * CH;
      if (a2 > avail) avail = a2;
    }

    __syncthreads();  // h(t0+CH) + next x_s visible; this chunk's ys stores drained
  }

  if (!LAST && tid == 0)
    __hip_atomic_store(prog_out, TT / CH, __ATOMIC_RELAXED, __HIP_MEMORY_SCOPE_AGENT);
}

__global__ __launch_bounds__(512, 2) void lstm_fused(
    const float* __restrict__ x, unsigned short* ys,
    const float* __restrict__ Wih0, const float* __restrict__ Whh0, const float* __restrict__ b0,
    const float* __restrict__ Wih1, const float* __restrict__ Whh1, const float* __restrict__ b1,
    const float* __restrict__ Wih2, const float* __restrict__ Whh2, const float* __restrict__ b2,
    float* __restrict__ hT, int* prog)
{
  __shared__ unsigned short x_s[CH * 16 * 128];
  __shared__ unsigned short h_s[2 * 16 * 128];
  __shared__ float b_s[512];
  const int lay = blockIdx.x >> 6;
  const int bblk = blockIdx.x & 63;
  if (lay == 0) {
    scan_layer<32, true, false>(x_s, h_s, b_s, x, ys, Wih0, Whh0, b0, nullptr,
                                nullptr, &prog[(0 * 64 + bblk) * 16], bblk);
  } else if (lay == 1) {
    scan_layer<128, false, false>(x_s, h_s, b_s, nullptr, ys, Wih1, Whh1, b1, nullptr,
                                  &prog[(0 * 64 + bblk) * 16], &prog[(1 * 64 + bblk) * 16], bblk);
  } else {
    scan_layer<128, false, true>(x_s, h_s, b_s, nullptr, ys, Wih2, Whh2, b2, hT,
                                 &prog[(1 * 64 + bblk) * 16], nullptr, bblk);
  }
}

__global__ void init_flags(int* prog) {
  prog[threadIdx.x] = 0;
  prog[threadIdx.x + 1024] = 0;
}

// ---------------------------------------------------------------------------
// Head: LN + fc1 + fc2 + 4 heads + reparam + dec1 + dec2 + out. 4 rows/block.
// ---------------------------------------------------------------------------
__global__ __launch_bounds__(256) void head_kernel(
    const float* __restrict__ hT, const float* __restrict__ eps,
    const float* __restrict__ u, const float* __restrict__ choice,
    const float* __restrict__ ln_g, const float* __restrict__ ln_b,
    const float* __restrict__ fc1_W, const float* __restrict__ fc1_b,
    const float* __restrict__ fc2_W, const float* __restrict__ fc2_b,
    const float* __restrict__ mean_W, const float* __restrict__ mean_b,
    const float* __restrict__ logvar_W, const float* __restrict__ logvar_b,
    const float* __restrict__ scale_W, const float* __restrict__ scale_b,
    const float* __restrict__ shape_W, const float* __restrict__ shape_b,
    const float* __restrict__ dec1_W, const float* __restrict__ dec1_b,
    const float* __restrict__ dec2_W, const float* __restrict__ dec2_b,
    const float* __restrict__ out_W, const float* __restrict__ out_b,
    const float* __restrict__ pi_params, float* __restrict__ out)
{
  __shared__ float s_hn[4][128];
  __shared__ float s_a[4][128];
  __shared__ float s_b2[4][64];
  __shared__ float s_z[4][64];
  __shared__ float s_d1[4][128];
  __shared__ float s_d2[4][512];

  const int tid = threadIdx.x;
  const int gr0 = blockIdx.x * 4;

  { // LayerNorm: one wave per row
    const int wvr = tid >> 6, lnn = tid & 63;
    const float v0 = hT[(gr0 + wvr) * 128 + lnn];
    const float v1 = hT[(gr0 + wvr) * 128 + 64 + lnn];
    float s = v0 + v1, s2 = v0 * v0 + v1 * v1;
#pragma unroll
    for (int off = 32; off; off >>= 1) {
      s  += __shfl_xor(s, off, 64);
      s2 += __shfl_xor(s2, off, 64);
    }
    const float mu  = s * (1.f / 128.f);
    const float var = s2 * (1.f / 128.f) - mu * mu;
    const float rs  = rsqrtf(var + 1e-5f);
    s_hn[wvr][lnn]      = (v0 - mu) * rs * ln_g[lnn]      + ln_b[lnn];
    s_hn[wvr][lnn + 64] = (v1 - mu) * rs * ln_g[lnn + 64] + ln_b[lnn + 64];
  }
  __syncthreads();
#pragma unroll
  for (int p = 0; p < 2; ++p) { // fc1 (128x128) + relu
    const int idx = tid + p * 256, row = idx >> 7, col = idx & 127;
    const float* w = fc1_W + col * 128;
    float a = fc1_b[col];
    for (int k = 0; k < 128; k += 4)
      a += s_hn[row][k] * w[k] + s_hn[row][k + 1] * w[k + 1] +
           s_hn[row][k + 2] * w[k + 2] + s_hn[row][k + 3] * w[k + 3];
    s_a[row][col] = fmaxf(a, 0.f);
  }
  __syncthreads();
  { // fc2 (64x128) + relu
    const int row = tid >> 6, col = tid & 63;
    const float* w = fc2_W + col * 128;
    float a = fc2_b[col];
    for (int k = 0; k < 128; ++k) a += s_a[row][k] * w[k];
    s_b2[row][col] = fmaxf(a, 0.f);
  }
  __syncthreads();
  { // 4 heads + reparameterize
    const int row = tid >> 6, c = tid & 63;
    const int gr = gr0 + row;
    float am = mean_b[c], al = logvar_b[c], as_ = scale_b[c], ah = shape_b[c];
    for (int k = 0; k < 64; ++k) {
      const float hv = s_b2[row][k];
      am  += hv * mean_W[c * 64 + k];
      al  += hv * logvar_W[c * 64 + k];
      as_ += hv * scale_W[c * 64 + k];
      ah  += hv * shape_W[c * 64 + k];
    }
    const float zsc = fexp2(as_ * LOG2E);
    const float zsh = fmaxf(ah, 1e-6f);
    out[131072 + gr * 64 + c] = am;
    out[196608 + gr * 64 + c] = al;
    out[262144 + gr * 64 + c] = zsc;
    out[327680 + gr * 64 + c] = zsh;
    const float ev = eps[gr * 64 + c], uv = u[gr * 64 + c], cv = choice[gr];
    const float zg = am + ev * fexp2(0.72134752044448170f * al);  // exp(0.5*logvar)
    const float p0 = pi_params[0], p1 = pi_params[1];
    const float pi0 = 1.f / (1.f + expf(p1 - p0));
    const float tq = -zsh * logf(1.f - uv);                       // expm1: no cancel
    const float zp = zsc * frcp(zsh) * expm1f(tq);
    s_z[row][c] = (cv < pi0) ? zg : zp;
  }
  __syncthreads();
#pragma unroll
  for (int p = 0; p < 2; ++p) { // dec1 (128x64) + relu
    const int idx = tid + p * 256, row = idx >> 7, col = idx & 127;
    const float* w = dec1_W + col * 64;
    float a = dec1_b[col];
    for (int k = 0; k < 64; ++k) a += s_z[row][k] * w[k];
    s_d1[row][col] = fmaxf(a, 0.f);
  }
  __syncthreads();
  for (int o = tid; o < 2000; o += 256) { // dec2 (500x128) + relu
    const int row = o / 500, col = o % 500;
    const float* w = dec2_W + col * 128;
    float a = dec2_b[col];
    for (int k = 0; k < 128; ++k) a += s_d1[row][k] * w[k];
    s_d2[row][col] = fmaxf(a, 0.f);
  }
  __syncthreads();
#pragma unroll
  for (int p = 0; p < 2; ++p) { // out (128x500)
    const int idx = tid + p * 256, row = idx >> 7, col = idx & 127;
    const float* w = out_W + col * 500;
    float a = out_b[col];
    for (int k = 0; k < 500; ++k) a += s_d2[row][k] * w[k];
    out[(gr0 + row) * 128 + col] = a;
  }
}

// ---------------------------------------------------------------------------
extern "C" void kernel_launch(void* const* d_in, const int* in_sizes, int n_in,
                              void* d_out, int out_size, void* d_ws, size_t ws_size,
                              hipStream_t stream) {
  const float* x      = (const float*)d_in[0];
  const float* eps    = (const float*)d_in[1];
  const float* u      = (const float*)d_in[2];
  const float* choice = (const float*)d_in[3];
  const float* Wih0 = (const float*)d_in[4],  *Whh0 = (const float*)d_in[5],  *b0 = (const float*)d_in[6];
  const float* Wih1 = (const float*)d_in[7],  *Whh1 = (const float*)d_in[8],  *b1 = (const float*)d_in[9];
  const float* Wih2 = (const float*)d_in[10], *Whh2 = (const float*)d_in[11], *b2 = (const float*)d_in[12];
  const float* ln_g = (const float*)d_in[13], *ln_b = (const float*)d_in[14];
  const float* fc1_W = (const float*)d_in[15], *fc1_b = (const float*)d_in[16];
  const float* fc2_W = (const float*)d_in[17], *fc2_b = (const float*)d_in[18];
  const float* mean_W = (const float*)d_in[19], *mean_b = (const float*)d_in[20];
  const float* logvar_W = (const float*)d_in[21], *logvar_b = (const float*)d_in[22];
  const float* scale_W = (const float*)d_in[23], *scale_b = (const float*)d_in[24];
  const float* shape_W = (const float*)d_in[25], *shape_b = (const float*)d_in[26];
  const float* dec1_W = (const float*)d_in[27], *dec1_b = (const float*)d_in[28];
  const float* dec2_W = (const float*)d_in[29], *dec2_b = (const float*)d_in[30];
  const float* out_W = (const float*)d_in[31], *out_b = (const float*)d_in[32];
  const float* pi_params = (const float*)d_in[33];

  unsigned short* ys = (unsigned short*)d_ws;                        // 128 MiB
  float* hT  = (float*)((char*)d_ws + (size_t)512 * 1024 * 128 * 2); // 512 KiB
  int*   prog = (int*)((char*)d_ws + (size_t)512 * 1024 * 128 * 2 + (size_t)1024 * 128 * 4);

  init_flags<<<1, 1024, 0, stream>>>(prog);
  lstm_fused<<<192, 512, 0, stream>>>(x, ys, Wih0, Whh0, b0, Wih1, Whh1, b1,
                                      Wih2, Whh2, b2, hT, prog);
  head_kernel<<<256, 256, 0, stream>>>(hT, eps, u, choice, ln_g, ln_b,
      fc1_W, fc1_b, fc2_W, fc2_b, mean_W, mean_b, logvar_W, logvar_b,
      scale_W, scale_b, shape_W, shape_b, dec1_W, dec1_b, dec2_W, dec2_b,
      out_W, out_b, pi_params, (float*)d_out);
}